// Round 2
// baseline (805.581 us; speedup 1.0000x reference)
//
#include <hip/hip_runtime.h>
#include <math.h>

#define V_ 128000
#define D_ 128
#define N_ 4
#define K_ 4
#define T_ 16
#define S_ 5
#define EPSF 1e-10f

// ws layout (float offsets)
#define WS_G      0          // [16][32][128][4] = 262144
#define WS_BEPS   262144     // [T][K][S][N][128] = 655360 ; after token t is consumed,
                             //   block k stashes fp32 eq rows into ITS OWN slice:
                             //   eq(t, kn=k*4+n) at WS_BEPS + t*10240 + k*2560 + n*128
#define WS_BX     917504     // [T][K][N][128] = 32768
#define WS_EQBALL 954368     // [T][4][64][8] ushort = 16384 floats
#define WS_INTER  977408     // [K][16] = 64
#define WS_WK     977472     // [T][16] = 256
#define WS_SRHO   977728     // [T] = 16
#define WS_LNZ    977744     // [T] = 16
#define WS_ZPART  977760     // [T][2000] float = 32000 (written by mega, read by zk)
#define WS_HPART  1009760    // [T][125] float = 2000

typedef __attribute__((ext_vector_type(8))) short short8v;
typedef __attribute__((ext_vector_type(4))) float float4v;

__device__ __forceinline__ short bfb(float x) {
    unsigned u = __float_as_uint(x);
    u += 0x7fffu + ((u >> 16) & 1u);
    return (short)(u >> 16);
}

// Jacobi round-robin pairing, closed form:
// lane 0: {15, r%15}; lane l=1..7: {(r+l)%15, (r-l)%15}
__device__ __forceinline__ void jpair(int x, int r, int& ox, bool& isp) {
    if (x == 15) { ox = r % 15; isp = true; return; }
    int s = x - r; s %= 15; if (s < 0) s += 15;
    if (s == 0) { ox = 15; isp = false; return; }
    int o = 2 * r - x; o %= 15; if (o < 0) o += 15;
    ox = o;
    isp = (s <= 7);
}

__device__ __forceinline__ void rotfast(float app, float aqq, float apq, float& c, float& s) {
    c = 1.f; s = 0.f;
    if (fabsf(apq) > 1e-20f) {
        float tau = (aqq - app) * 0.5f * __builtin_amdgcn_rcpf(apq);
        float sq1 = __builtin_amdgcn_sqrtf(1.f + tau * tau);
        float den = tau + ((tau >= 0.f) ? sq1 : -sq1);
        float tt = __builtin_amdgcn_rcpf(den);
        c = __builtin_amdgcn_rsqf(1.f + tt * tt);
        s = tt * c;
    }
}

// ---------------- init: blocks 0-63 = G/Bx/beps prep; block 64 = interaction ----------------
__global__ __launch_bounds__(256)
void i2_prep(const float* __restrict__ bases, const float* __restrict__ E,
             const float* __restrict__ noise, const int* __restrict__ tokens,
             const float* __restrict__ tension, const float* __restrict__ temperature,
             float* __restrict__ ws)
{
    int tid = threadIdx.x;
    if (blockIdx.x == 64) {
        if (tid < 4) {
            int k = tid;
            float temp = fmaxf(fabsf(temperature[k]), 0.01f);
            for (int i = 0; i < 4; ++i) {
                float v[4]; float mx = -1e30f;
                for (int j = 0; j < 4; ++j) { v[j] = -tension[k*16 + i*4 + j] / temp; mx = fmaxf(mx, v[j]); }
                float se = 0.f;
                for (int j = 0; j < 4; ++j) { v[j] = expf(v[j] - mx); se += v[j]; }
                for (int j = 0; j < 4; ++j) ws[WS_INTER + k*16 + i*4 + j] = (i == j) ? 0.0f : v[j] / se;
            }
        }
        return;
    }
    int kn = blockIdx.x >> 2, q = blockIdx.x & 3;
    int k = kn >> 2, n = kn & 3;
    __shared__ __align__(16) float Blds[128 * 132];
    const float4* B4 = (const float4*)(bases + (size_t)kn * 16384);
    for (int idx = tid; idx < 4096; idx += 256) {
        int jrow = idx >> 5, c = idx & 31;
        float4 v = B4[jrow * 32 + c];
        *((float4*)&Blds[jrow * 132 + c * 4]) = v;
    }
    __syncthreads();
    int j1 = q * 32 + (tid >> 3);
    int l = tid & 7;
    float accg[16];
#pragma unroll
    for (int i = 0; i < 16; ++i) accg[i] = 0.f;
    for (int c = 0; c < 32; ++c) {
        float4 b1 = *((const float4*)&Blds[j1 * 132 + c * 4]);
#pragma unroll
        for (int i = 0; i < 16; ++i) {
            float4 b2 = *((const float4*)&Blds[(l + 8 * i) * 132 + c * 4]);
            accg[i] += b1.x * b2.x + b1.y * b2.y + b1.z * b2.z + b1.w * b2.w;
        }
    }
#pragma unroll
    for (int i = 0; i < 16; ++i) {
        int j2 = l + 8 * i;
        ws[WS_G + (((size_t)kn * 32 + (j2 >> 2)) * 128 + j1) * 4 + (j2 & 3)] = accg[i];
    }
    __shared__ __align__(16) float vecl[128];
    __shared__ float vred[2][128];
    int jv = tid & 127, ch = tid >> 7;
    for (int vi = q * 24; vi < q * 24 + 24; ++vi) {
        const float* src; int dstoff;
        if (vi < 16) {
            int tt = vi;
            src = E + (size_t)tokens[tt] * 128;
            dstoff = WS_BX + (tt * 4 + k) * 512 + n * 128;
        } else {
            int r2 = vi - 16; int tt = r2 / 5, s2 = r2 % 5;
            size_t off = (size_t)(((tt * 4 + k) * 5 + s2) * 4 + n) * 128;
            src = noise + off;
            dstoff = WS_BEPS + (int)off;
        }
        if (tid < 32) ((float4*)vecl)[tid] = ((const float4*)src)[tid];
        __syncthreads();
        float a2 = 0.f;
        for (int c = ch * 16; c < ch * 16 + 16; ++c) {
            float4 bv = *((const float4*)&Blds[jv * 132 + c * 4]);
            float4 xv = ((const float4*)vecl)[c];
            a2 += bv.x * xv.x + bv.y * xv.y + bv.z * xv.z + bv.w * xv.w;
        }
        vred[ch][jv] = a2;
        __syncthreads();
        if (tid < 128) ws[dstoff + tid] = vred[0][tid] + vred[1][tid];
        __syncthreads();
    }
}

// ---------------- kap_all: 4 blocks x 256 threads, wave n = bubble n, lane owns d, d+64 ----------------
// All per-step reductions intra-wave; cross-wave exchange = 2 floats/bubble/step.
// 2 barriers per s-step; bmm in registers; Gram removed (eq fp32 stashed in own beps slice).
__global__ __launch_bounds__(256, 1)
void kap_all(const float* __restrict__ E, const float* __restrict__ noise,
             const int* __restrict__ tokens, const float* __restrict__ bases,
             const float* __restrict__ target_sim, const float* __restrict__ step_size,
             const float* __restrict__ gate_logit, const float* __restrict__ decay_base,
             const float* __restrict__ sensitivity, float* __restrict__ ws)
{
    const int k = blockIdx.x;
    const int tid = threadIdx.x;
    const int n = tid >> 6;          // bubble = wave
    const int lane = tid & 63;
    const int d0 = lane, d1 = lane + 64;
    const int kn = k * 4 + n;

    __shared__ float xl[128];
    __shared__ __align__(16) float mlL[128];
    __shared__ __align__(16) float aL[4][128], exL[4][128];
    __shared__ float interL[16];
    __shared__ float diagP[4], sP[4], sq7[4];

    // G rows d0, d1 — loaded ONCE for all 16 tokens (256 VGPR)
    float4 g0[32], g1[32];
    const float4* G4 = (const float4*)(ws + WS_G);
#pragma unroll
    for (int c = 0; c < 32; ++c) {
        g0[c] = G4[((size_t)kn * 32 + c) * 128 + d0];
        g1[c] = G4[((size_t)kn * 32 + c) * 128 + d1];
    }

    if (tid < 16) interL[tid] = ws[WS_INTER + k * 16 + tid];
    if (tid < 128) mlL[tid] = 0.f;

    const float tgt = target_sim[k];
    const float stp = fminf(fmaxf(fabsf(step_size[k]), 0.001f), 0.5f);
    const float gate = 1.0f / (1.0f + expf(-gate_logit[k]));
    const float dbase = decay_base[0];
    const float sens = fabsf(sensitivity[0]);

    float xr = (tid < 128) ? E[(size_t)tokens[0] * 128 + tid] : 0.f;
    float bmm0 = 0.f, bmm1 = 0.f;
    __syncthreads();
    float w_inter[4];
#pragma unroll
    for (int m = 0; m < 4; ++m) w_inter[m] = interL[n * 4 + m];

#pragma unroll 1
    for (int t = 0; t < T_; ++t) {
        if (tid < 128) xl[tid] = xr;
        __syncthreads();                               // B1: xl (mlL covered by prev F2)
        if (t + 1 < T_ && tid < 128) xr = E[(size_t)tokens[t + 1] * 128 + tid];  // prefetch

        // prefetch all 5 steps' beps/noise + Bx (issued early, land under the chain)
        float bep0[5], bep1[5], no0[5], no1[5];
#pragma unroll
        for (int s = 0; s < 5; ++s) {
            int nz = (((t * 4 + k) * 5 + s) * 4 + n) * 128;
            bep0[s] = ws[WS_BEPS + nz + d0]; bep1[s] = ws[WS_BEPS + nz + d1];
            no0[s] = noise[nz + d0];         no1[s] = noise[nz + d1];
        }
        float bx0 = ws[WS_BX + (t * 4 + k) * 512 + n * 128 + d0];
        float bx1 = ws[WS_BX + (t * 4 + k) * 512 + n * 128 + d1];

        // novelty / decay — computed redundantly in every wave (no broadcast barrier)
        float x0 = xl[d0], x1 = xl[d1], m0 = mlL[d0], m1 = mlL[d1];
        float vx = x0 * x0 + x1 * x1, vm = m0 * m0 + m1 * m1, vd = x0 * m0 + x1 * m1;
        for (int m = 32; m; m >>= 1) { vx += __shfl_xor(vx, m); vm += __shfl_xor(vm, m); vd += __shfl_xor(vd, m); }
        float xnorm = sqrtf(vx) + EPSF, mnorm = sqrtf(vm) + EPSF;
        float nov = 1.0f - vd / (xnorm * mnorm);
        float novelty = (mnorm > 1e-8f) ? nov : 1.0f;
        const float dec = 1.0f / (1.0f + expf(-(dbase - sens * novelty)));

        float e00 = bx0 + dec * bmm0, e01 = bx1 + dec * bmm1;
        float u0 = x0 + dec * m0, u1 = x1 + dec * m1;
        float ex0 = e00, ex1 = e01, a0 = 0.f, a1 = 0.f, be0 = 0.f, be1 = 0.f;
        exL[n][d0] = ex0; exL[n][d1] = ex1;
        __syncthreads();                               // B2: exL init

        for (int s = 0; s < 5; ++s) {
            float em0[4], em1[4];
#pragma unroll
            for (int m = 0; m < 4; ++m) { em0[m] = exL[m][d0]; em1[m] = exL[m][d1]; }
            float r[7];
#pragma unroll
            for (int m = 0; m < 4; ++m) r[m] = ex0 * em0[m] + ex1 * em1[m];
            r[4] = u0 * u0 + u1 * u1;
            r[5] = (e00 + be0) * a0 + (e01 + be1) * a1;
            r[6] = a0 * (ex0 - e00 - be0) + a1 * (ex1 - e01 - be1);
#pragma unroll
            for (int m2 = 32; m2; m2 >>= 1) {
#pragma unroll
                for (int q = 0; q < 7; ++q) r[q] += __shfl_xor(r[q], m2);
            }
            float sn = sqrtf(fmaxf(r[4] + 2.f * r[5] + r[6], 0.f));
            if (lane == 0) { diagP[n] = r[n]; sP[n] = sn; }
            __syncthreads();                           // B3: 8-float exchange
            float ssum = ((sP[0] + sP[1]) + sP[2]) + sP[3];
            float cn = gate * (0.25f * ssum + EPSF) * 0.01f;

            float Pnn = r[n];
            float enn = sqrtf(fmaxf(Pnn, 0.f)) + EPSF;
            float fsh0 = 0.f, fsh1 = 0.f;
#pragma unroll
            for (int m = 0; m < 4; ++m) {
                float Pmm = diagP[m];
                float Pnm = r[m];
                float enm = sqrtf(fmaxf(Pmm, 0.f)) + EPSF;
                float cosnm = Pnm / (enn * enm);
                float fm = (cosnm - tgt) * w_inter[m];
                float dnn = sqrtf(fmaxf(Pnn - 2.f * Pnm + Pmm, 0.f)) + EPSF;
                float w = fm / dnn;
                fsh0 += w * (ex0 - em0[m]);
                fsh1 += w * (ex1 - em1[m]);
            }
            a0 += stp * fsh0; a1 += stp * fsh1;
            be0 += cn * bep0[s]; be1 += cn * bep1[s];
            u0 += cn * no0[s];   u1 += cn * no1[s];
            aL[n][d0] = a0; aL[n][d1] = a1;
            // wave-synchronous LDS: write+read by the same wave, no barrier needed
            const float4* a4 = (const float4*)aL[n];
            float y0 = 0.f, y1 = 0.f;
#pragma unroll
            for (int c = 0; c < 32; ++c) {
                float4 av = a4[c];
                y0 += g0[c].x * av.x + g0[c].y * av.y + g0[c].z * av.z + g0[c].w * av.w;
                y1 += g1[c].x * av.x + g1[c].y * av.y + g1[c].z * av.z + g1[c].w * av.w;
            }
            ex0 = e00 + y0 + be0; ex1 = e01 + y1 + be1;
            exL[n][d0] = ex0; exL[n][d1] = ex1;
            __syncthreads();                           // B4: exL for next step
        }

        // eq[d] = u[d] + sum_j a[j] * B[j][d]  (aL intra-wave; B column stream coalesced)
        {
            const float* Bp = bases + (size_t)kn * 16384;
            float acc0 = 0.f, acc1 = 0.f;
#pragma unroll 8
            for (int j = 0; j < 128; ++j) {
                float aj = aL[n][j];
                acc0 += aj * Bp[(size_t)j * 128 + d0];
                acc1 += aj * Bp[(size_t)j * 128 + d1];
            }
            float eq0 = u0 + acc0, eq1 = u1 + acc1;
            // fp32 eq stash into this block's OWN consumed beps slice (for Gram in mega)
            int eqfbase = WS_BEPS + t * 10240 + k * 2560 + n * 128;
            ws[eqfbase + d0] = eq0; ws[eqfbase + d1] = eq1;
            unsigned short* eqb = (unsigned short*)(ws + WS_EQBALL);
            {
                int c2 = d0 >> 5, lg = (d0 >> 3) & 3, j8 = d0 & 7;
                eqb[t * 2048 + (c2 * 64 + lg * 16 + kn) * 8 + j8] = (unsigned short)bfb(eq0);
            }
            {
                int c2 = d1 >> 5, lg = (d1 >> 3) & 3, j8 = d1 & 7;
                eqb[t * 2048 + (c2 * 64 + lg * 16 + kn) * 8 + j8] = (unsigned short)bfb(eq1);
            }
            float sq = eq0 * eq0 + eq1 * eq1;
            for (int m = 32; m; m >>= 1) sq += __shfl_xor(sq, m);
            if (lane == 0) sq7[n] = sq;
            exL[n][d0] = eq0; exL[n][d1] = eq1;
            __syncthreads();                           // F1: eq + sq visible
            if (tid < 4) {
                float s4 = sq7[0] + sq7[1] + sq7[2] + sq7[3];
                ws[WS_WK + t * 16 + 4 * k + tid] = 1.0f / (4.0f * (s4 + EPSF));
            }
            if (tid < 128) {
                float eqm = 0.25f * (exL[0][tid] + exL[1][tid] + exL[2][tid] + exL[3][tid]);
                mlL[tid] = dec * mlL[tid] + (1.f - dec) * eqm;
            }
            __syncthreads();                           // F2: mm
            // bmm rows d0,d1 stay in REGISTERS (only this lane reads them next token)
            const float4* Br0 = (const float4*)(bases + (size_t)kn * 16384 + (size_t)d0 * 128);
            const float4* Br1 = (const float4*)(bases + (size_t)kn * 16384 + (size_t)d1 * 128);
            const float4* mm4 = (const float4*)mlL;
            bmm0 = 0.f; bmm1 = 0.f;
#pragma unroll 8
            for (int c = 0; c < 32; ++c) {
                float4 mv = mm4[c];
                float4 v0 = Br0[c], v1 = Br1[c];
                bmm0 += v0.x * mv.x + v0.y * mv.y + v0.z * mv.z + v0.w * mv.w;
                bmm1 += v1.x * mv.x + v1.y * mv.y + v1.z * mv.z + v1.w * mv.w;
            }
        }
    }
}

// ---------------- mega: blocks 0-15 = Gram+Jacobi (overlap GEMM); 16+ = logits GEMM, 8 tokens/block ----------------
__global__ __launch_bounds__(256, 2)
void mega(const float* __restrict__ E, float* __restrict__ ws, float* __restrict__ out)
{
    int b = blockIdx.x, tid = threadIdx.x;
    if (b < 16) {
        int tt = b;
        __shared__ float Gsh[256];
        __shared__ float Am[16 * 20];
        __shared__ float cR[16], sR[16];
        {   // Gram from fp32 eq stash (all 256 threads, one entry each)
            int i = tid >> 4, j = tid & 15;
            const float4* ra = (const float4*)(ws + WS_BEPS + tt * 10240 + (i >> 2) * 2560 + (i & 3) * 128);
            const float4* rb = (const float4*)(ws + WS_BEPS + tt * 10240 + (j >> 2) * 2560 + (j & 3) * 128);
            float dp = 0.f;
#pragma unroll 8
            for (int c = 0; c < 32; ++c) {
                float4 a = ra[c], b2 = rb[c];
                dp += a.x * b2.x + a.y * b2.y + a.z * b2.z + a.w * b2.w;
            }
            Gsh[tid] = dp;
        }
        __syncthreads();
        if (tid >= 64) return;
        const float* G = Gsh;
        int i0 = tid >> 2, j40 = (tid & 3) * 4;
        float wv4[4];
#pragma unroll
        for (int kk = 0; kk < 4; ++kk) {
            float ss = G[(4*kk+0)*17] + G[(4*kk+1)*17] + G[(4*kk+2)*17] + G[(4*kk+3)*17];
            wv4[kk] = 1.0f / (4.0f * (ss + EPSF));
        }
#pragma unroll
        for (int m = 0; m < 4; ++m) {
            int jjv = j40 + m;
            Am[i0 * 20 + jjv] = sqrtf(wv4[i0 >> 2] * wv4[jjv >> 2]) * G[i0 * 16 + jjv];
        }
        for (int sw = 0; sw < 6; ++sw) {
            for (int r = 0; r < 15; ++r) {
                if (tid < 8) {
                    int p, q;
                    if (tid == 0) { p = 15; q = r % 15; }
                    else { p = (r + tid) % 15; q = (r - tid + 15) % 15; }
                    float c, s;
                    rotfast(Am[p * 20 + p], Am[q * 20 + q], Am[p * 20 + q], c, s);
                    cR[p] = c; sR[p] = -s;
                    cR[q] = c; sR[q] = s;
                }
                int oi; bool ip; jpair(i0, r, oi, ip);
                float ci = cR[i0], siS = sR[i0];
                float nv[4];
#pragma unroll
                for (int m = 0; m < 4; ++m) {
                    int jjv = j40 + m;
                    int oj; bool jp2; jpair(jjv, r, oj, jp2);
                    float cj = cR[jjv], sjS = sR[jjv];
                    float a00 = Am[i0 * 20 + jjv], a01 = Am[i0 * 20 + oj];
                    float a10 = Am[oi * 20 + jjv], a11 = Am[oi * 20 + oj];
                    nv[m] = ci*cj*a00 + ci*sjS*a01 + siS*cj*a10 + siS*sjS*a11;
                }
#pragma unroll
                for (int m = 0; m < 4; ++m) Am[i0 * 20 + j40 + m] = nv[m];
            }
        }
        if (tid == 0) {
            float tot = 112.0f * 1e-12f;
            float lc[16];
            for (int a2 = 0; a2 < 16; ++a2) { lc[a2] = fmaxf(Am[a2 * 20 + a2], 1e-12f); tot += lc[a2]; }
            float S = 0.f;
            for (int a2 = 0; a2 < 16; ++a2) { float pp = lc[a2] / tot; S -= pp * fmaxf(logf(pp), -100.f); }
            float p0 = 1e-12f / tot;
            S -= 112.f * p0 * fmaxf(logf(p0), -100.f);
            out[(size_t)T_ * V_ + tt] = S;
            ws[WS_SRHO + tt] = S;
        }
        return;
    }
    int b2 = b - 16;
    int pass = b2 / 500;                 // 0 or 1
    int bb = b2 - pass * 500;
    int tok0 = pass * 8;
    int lane = tid & 63, wv = tid >> 6;
    const short8v* eqB = (const short8v*)(ws + WS_EQBALL);
    short8v bfr[8][4];
#pragma unroll
    for (int tk = 0; tk < 8; ++tk)
#pragma unroll
        for (int c2 = 0; c2 < 4; ++c2) bfr[tk][c2] = eqB[(tok0 + tk) * 256 + c2 * 64 + lane];
    float wk[8], zl[8];
#pragma unroll
    for (int tk = 0; tk < 8; ++tk) {
        wk[tk] = ws[WS_WK + (tok0 + tk) * 16 + (lane & 15)];
        zl[tk] = 0.f;
    }
    int tilebase = (bb * 4 + wv) * 64;
#pragma unroll
    for (int it = 0; it < 4; ++it) {
        int rowB = tilebase + it * 16;
        const float* Erow = E + (size_t)(rowB + (lane & 15)) * 128 + ((lane >> 4) * 8);
        float4v acc[8];
#pragma unroll
        for (int tk = 0; tk < 8; ++tk) acc[tk] = (float4v){0.f, 0.f, 0.f, 0.f};
#pragma unroll
        for (int c2 = 0; c2 < 4; ++c2) {
            float4 e0 = *((const float4*)(Erow + c2 * 32));
            float4 e1 = *((const float4*)(Erow + c2 * 32 + 4));
            short8v a;
            a[0] = bfb(e0.x); a[1] = bfb(e0.y); a[2] = bfb(e0.z); a[3] = bfb(e0.w);
            a[4] = bfb(e1.x); a[5] = bfb(e1.y); a[6] = bfb(e1.z); a[7] = bfb(e1.w);
#pragma unroll
            for (int tk = 0; tk < 8; ++tk)
                acc[tk] = __builtin_amdgcn_mfma_f32_16x16x32_bf16(a, bfr[tk][c2], acc[tk], 0, 0, 0);
        }
#pragma unroll
        for (int tk = 0; tk < 8; ++tk) {
            float l0 = wk[tk] * acc[tk][0] * acc[tk][0];
            float l1 = wk[tk] * acc[tk][1] * acc[tk][1];
            float l2 = wk[tk] * acc[tk][2] * acc[tk][2];
            float l3 = wk[tk] * acc[tk][3] * acc[tk][3];
#pragma unroll
            for (int m = 1; m <= 8; m <<= 1) {
                l0 += __shfl_xor(l0, m); l1 += __shfl_xor(l1, m);
                l2 += __shfl_xor(l2, m); l3 += __shfl_xor(l3, m);
            }
            if ((lane & 15) == 0) {
                float4 st; st.x = l0; st.y = l1; st.z = l2; st.w = l3;
                *((float4*)(out + (size_t)(tok0 + tk) * V_ + rowB + (lane >> 4) * 4)) = st;
                zl[tk] += __expf(l0) + __expf(l1) + __expf(l2) + __expf(l3);
            }
        }
    }
#pragma unroll
    for (int tk = 0; tk < 8; ++tk) {
        float z = zl[tk];
        z += __shfl_xor(z, 16); z += __shfl_xor(z, 32);
        if (lane == 0) ws[WS_ZPART + (tok0 + tk) * 2000 + bb * 4 + wv] = z;
    }
}

// ---------------- zk: Z reduce per token ----------------
__global__ __launch_bounds__(256)
void zk(float* __restrict__ ws)
{
    int b = blockIdx.x, tid = threadIdx.x;
    double s = 0.0;
    for (int i = tid; i < 2000; i += 256) s += (double)ws[WS_ZPART + b * 2000 + i];
    for (int m = 32; m; m >>= 1) s += __shfl_xor(s, m);
    __shared__ double sr[4];
    if ((tid & 63) == 0) sr[tid >> 6] = s;
    __syncthreads();
    if (tid == 0) ws[WS_LNZ + b] = (float)log(sr[0] + sr[1] + sr[2] + sr[3]);
}

// ---------------- fin1: probs + per-block H partials (pure streaming) ----------------
__global__ __launch_bounds__(256)
void fin1(float* __restrict__ ws, float* __restrict__ out)
{
    int b = blockIdx.x, tid = threadIdx.x;
    int tt = b / 125, blk = b - tt * 125;
    int v = blk * 1024 + tid * 4;
    float lnZ = ws[WS_LNZ + tt];
    float* po = out + (size_t)tt * V_ + v;
    float4 l4 = *((const float4*)po);
    float lp0 = l4.x - lnZ, lp1 = l4.y - lnZ, lp2 = l4.z - lnZ, lp3 = l4.w - lnZ;
    float p0 = __expf(lp0), p1 = __expf(lp1), p2 = __expf(lp2), p3 = __expf(lp3);
    float4 st; st.x = p0; st.y = p1; st.z = p2; st.w = p3;
    *((float4*)po) = st;
    float hp = p0 * fmaxf(lp0, -100.f) + p1 * fmaxf(lp1, -100.f)
             + p2 * fmaxf(lp2, -100.f) + p3 * fmaxf(lp3, -100.f);
    for (int m = 32; m; m >>= 1) hp += __shfl_xor(hp, m);
    __shared__ float hr[4];
    if ((tid & 63) == 0) hr[tid >> 6] = hp;
    __syncthreads();
    if (tid == 0) ws[WS_HPART + tt * 125 + blk] = hr[0] + hr[1] + hr[2] + hr[3];
}

// ---------------- f2: per-token H reduction ----------------
__global__ __launch_bounds__(128)
void f2_final(float* __restrict__ ws, float* __restrict__ out)
{
    int t = blockIdx.x, tid = threadIdx.x;
    float s = (tid < 125) ? ws[WS_HPART + t * 125 + tid] : 0.f;
    for (int m = 32; m; m >>= 1) s += __shfl_xor(s, m);
    __shared__ float sr[2];
    if ((tid & 63) == 0) sr[tid >> 6] = s;
    __syncthreads();
    if (tid == 0) {
        float H = -(sr[0] + sr[1]);
        float S = ws[WS_SRHO + t];
        out[(size_t)T_ * V_ + T_ + t] = H;
        out[(size_t)T_ * V_ + 2 * T_ + t] = H - S;
    }
}

extern "C" void kernel_launch(void* const* d_in, const int* in_sizes, int n_in,
                              void* d_out, int out_size, void* d_ws, size_t ws_size,
                              hipStream_t stream)
{
    (void)in_sizes; (void)n_in; (void)out_size; (void)ws_size;
    const float* E           = (const float*)d_in[0];
    const float* bases       = (const float*)d_in[1];
    const float* tension     = (const float*)d_in[2];
    const float* temperature = (const float*)d_in[3];
    const float* target_sim  = (const float*)d_in[4];
    const float* step_size   = (const float*)d_in[5];
    const float* gate_logit  = (const float*)d_in[6];
    const float* decay_base  = (const float*)d_in[7];
    const float* sensitivity = (const float*)d_in[8];
    const float* noise       = (const float*)d_in[9];
    const int*   tokens      = (const int*)d_in[10];
    float* out = (float*)d_out;
    float* ws  = (float*)d_ws;

    i2_prep<<<65, 256, 0, stream>>>(bases, E, noise, tokens, tension, temperature, ws);
    kap_all<<<4, 256, 0, stream>>>(E, noise, tokens, bases, target_sim, step_size,
                                   gate_logit, decay_base, sensitivity, ws);
    mega<<<1016, 256, 0, stream>>>(E, ws, out);
    zk<<<16, 256, 0, stream>>>(ws);
    fin1<<<T_ * 125, 256, 0, stream>>>(ws, out);
    f2_final<<<T_, 128, 0, stream>>>(ws, out);
}

// Round 3
// 599.849 us; speedup vs baseline: 1.3430x; 1.3430x over previous
//
#include <hip/hip_runtime.h>
#include <math.h>

#define V_ 128000
#define D_ 128
#define N_ 4
#define K_ 4
#define T_ 16
#define S_ 5
#define EPSF 1e-10f

// ws layout (float offsets)
#define WS_G      0          // [16][32][128][4] = 262144
#define WS_BEPS   262144     // [T][K][S][N][128] = 655360 ; after token t is consumed,
                             //   block k stashes fp32 eq rows into ITS OWN slice:
                             //   eq(t, kn=k*4+n) at WS_BEPS + t*10240 + k*2560 + n*128
#define WS_BX     917504     // [T][K][N][128] = 32768
#define WS_EQBALL 954368     // [T][4][64][8] ushort = 16384 floats
#define WS_INTER  977408     // [K][16] = 64
#define WS_WK     977472     // [T][16] = 256
#define WS_SRHO   977728     // [T] = 16
#define WS_LNZ    977744     // [T] = 16
#define WS_ZPART  977760     // [T][2000] float = 32000 (written by mega, read by zk)
#define WS_HPART  1009760    // [T][125] float = 2000

typedef __attribute__((ext_vector_type(8))) short short8v;
typedef __attribute__((ext_vector_type(4))) float float4v;

__device__ __forceinline__ short bfb(float x) {
    unsigned u = __float_as_uint(x);
    u += 0x7fffu + ((u >> 16) & 1u);
    return (short)(u >> 16);
}

// Jacobi round-robin pairing, closed form:
// lane 0: {15, r%15}; lane l=1..7: {(r+l)%15, (r-l)%15}
__device__ __forceinline__ void jpair(int x, int r, int& ox, bool& isp) {
    if (x == 15) { ox = r % 15; isp = true; return; }
    int s = x - r; s %= 15; if (s < 0) s += 15;
    if (s == 0) { ox = 15; isp = false; return; }
    int o = 2 * r - x; o %= 15; if (o < 0) o += 15;
    ox = o;
    isp = (s <= 7);
}

__device__ __forceinline__ void rotfast(float app, float aqq, float apq, float& c, float& s) {
    c = 1.f; s = 0.f;
    if (fabsf(apq) > 1e-20f) {
        float tau = (aqq - app) * 0.5f * __builtin_amdgcn_rcpf(apq);
        float sq1 = __builtin_amdgcn_sqrtf(1.f + tau * tau);
        float den = tau + ((tau >= 0.f) ? sq1 : -sq1);
        float tt = __builtin_amdgcn_rcpf(den);
        c = __builtin_amdgcn_rsqf(1.f + tt * tt);
        s = tt * c;
    }
}

// ---------------- init: blocks 0-63 = G/Bx/beps prep; block 64 = interaction ----------------
__global__ __launch_bounds__(256)
void i2_prep(const float* __restrict__ bases, const float* __restrict__ E,
             const float* __restrict__ noise, const int* __restrict__ tokens,
             const float* __restrict__ tension, const float* __restrict__ temperature,
             float* __restrict__ ws)
{
    int tid = threadIdx.x;
    if (blockIdx.x == 64) {
        if (tid < 4) {
            int k = tid;
            float temp = fmaxf(fabsf(temperature[k]), 0.01f);
            for (int i = 0; i < 4; ++i) {
                float v[4]; float mx = -1e30f;
                for (int j = 0; j < 4; ++j) { v[j] = -tension[k*16 + i*4 + j] / temp; mx = fmaxf(mx, v[j]); }
                float se = 0.f;
                for (int j = 0; j < 4; ++j) { v[j] = expf(v[j] - mx); se += v[j]; }
                for (int j = 0; j < 4; ++j) ws[WS_INTER + k*16 + i*4 + j] = (i == j) ? 0.0f : v[j] / se;
            }
        }
        return;
    }
    int kn = blockIdx.x >> 2, q = blockIdx.x & 3;
    int k = kn >> 2, n = kn & 3;
    __shared__ __align__(16) float Blds[128 * 132];
    const float4* B4 = (const float4*)(bases + (size_t)kn * 16384);
    for (int idx = tid; idx < 4096; idx += 256) {
        int jrow = idx >> 5, c = idx & 31;
        float4 v = B4[jrow * 32 + c];
        *((float4*)&Blds[jrow * 132 + c * 4]) = v;
    }
    __syncthreads();
    int j1 = q * 32 + (tid >> 3);
    int l = tid & 7;
    float accg[16];
#pragma unroll
    for (int i = 0; i < 16; ++i) accg[i] = 0.f;
    for (int c = 0; c < 32; ++c) {
        float4 b1 = *((const float4*)&Blds[j1 * 132 + c * 4]);
#pragma unroll
        for (int i = 0; i < 16; ++i) {
            float4 b2 = *((const float4*)&Blds[(l + 8 * i) * 132 + c * 4]);
            accg[i] += b1.x * b2.x + b1.y * b2.y + b1.z * b2.z + b1.w * b2.w;
        }
    }
#pragma unroll
    for (int i = 0; i < 16; ++i) {
        int j2 = l + 8 * i;
        ws[WS_G + (((size_t)kn * 32 + (j2 >> 2)) * 128 + j1) * 4 + (j2 & 3)] = accg[i];
    }
    __shared__ __align__(16) float vecl[128];
    __shared__ float vred[2][128];
    int jv = tid & 127, ch = tid >> 7;
    for (int vi = q * 24; vi < q * 24 + 24; ++vi) {
        const float* src; int dstoff;
        if (vi < 16) {
            int tt = vi;
            src = E + (size_t)tokens[tt] * 128;
            dstoff = WS_BX + (tt * 4 + k) * 512 + n * 128;
        } else {
            int r2 = vi - 16; int tt = r2 / 5, s2 = r2 % 5;
            size_t off = (size_t)(((tt * 4 + k) * 5 + s2) * 4 + n) * 128;
            src = noise + off;
            dstoff = WS_BEPS + (int)off;
        }
        if (tid < 32) ((float4*)vecl)[tid] = ((const float4*)src)[tid];
        __syncthreads();
        float a2 = 0.f;
        for (int c = ch * 16; c < ch * 16 + 16; ++c) {
            float4 bv = *((const float4*)&Blds[jv * 132 + c * 4]);
            float4 xv = ((const float4*)vecl)[c];
            a2 += bv.x * xv.x + bv.y * xv.y + bv.z * xv.z + bv.w * xv.w;
        }
        vred[ch][jv] = a2;
        __syncthreads();
        if (tid < 128) ws[dstoff + tid] = vred[0][tid] + vred[1][tid];
        __syncthreads();
    }
}

// ---------------- kap_all: 4 blocks x 512 threads ----------------
// wave w = (bubble n = w&3, half h = w>>2). Each lane holds the FULL bubble
// (dims lane, lane+64) DUPLICATED across halves -> all reductions intra-wave.
// Halves split only the output dim (dG = 64h+lane) of the GEMV/finalize.
// 2 barriers per s-step; cross-bubble coupling = 8 floats (diag + norm).
__global__ __launch_bounds__(512, 2)
void kap_all(const float* __restrict__ E, const float* __restrict__ noise,
             const int* __restrict__ tokens, const float* __restrict__ bases,
             const float* __restrict__ target_sim, const float* __restrict__ step_size,
             const float* __restrict__ gate_logit, const float* __restrict__ decay_base,
             const float* __restrict__ sensitivity, float* __restrict__ ws)
{
    const int k = blockIdx.x;
    const int tid = threadIdx.x;
    const int w = tid >> 6;
    const int n = w & 3;             // bubble
    const int h = w >> 2;            // half (output-dim split)
    const int lane = tid & 63;
    const int d0 = lane, d1 = lane + 64;
    const int dG = h * 64 + lane;    // owned output dim
    const int kn = k * 4 + n;

    __shared__ float xl[128];
    __shared__ float mlL[128];
    __shared__ __align__(16) float aL[4][128];
    __shared__ float exL[4][128];
    __shared__ float bmmL[4][128];
    __shared__ float interL[16];
    __shared__ float diagP[4], sP[4];
    __shared__ float sq7[4][2];

    // G column dG (128 VGPR) — loaded ONCE for all 16 tokens
    float4 gg[32];
    const float4* G4 = (const float4*)(ws + WS_G);
#pragma unroll
    for (int c = 0; c < 32; ++c) gg[c] = G4[((size_t)kn * 32 + c) * 128 + dG];

    if (tid < 16) interL[tid] = ws[WS_INTER + k * 16 + tid];
    if (tid < 128) mlL[tid] = 0.f;
    bmmL[n][dG] = 0.f;

    const float tgt = target_sim[k];
    const float stp = fminf(fmaxf(fabsf(step_size[k]), 0.001f), 0.5f);
    const float gate = 1.0f / (1.0f + expf(-gate_logit[k]));
    const float dbase = decay_base[0];
    const float sens = fabsf(sensitivity[0]);

    float xr = (tid < 128) ? E[(size_t)tokens[0] * 128 + tid] : 0.f;
    __syncthreads();
    float w_inter[4];
#pragma unroll
    for (int m = 0; m < 4; ++m) w_inter[m] = interL[n * 4 + m];

#pragma unroll 1
    for (int t = 0; t < T_; ++t) {
        if (tid < 128) xl[tid] = xr;
        __syncthreads();                               // B1: xl (+prev bmmL/mlL)
        if (t + 1 < T_ && tid < 128) xr = E[(size_t)tokens[t + 1] * 128 + tid];

        // prefetch all 5 steps' beps/noise + Bx
        float bep0[5], bep1[5], no0[5], no1[5];
#pragma unroll
        for (int s = 0; s < 5; ++s) {
            int nz = (((t * 4 + k) * 5 + s) * 4 + n) * 128;
            bep0[s] = ws[WS_BEPS + nz + d0]; bep1[s] = ws[WS_BEPS + nz + d1];
            no0[s] = noise[nz + d0];         no1[s] = noise[nz + d1];
        }
        float bx0 = ws[WS_BX + (t * 4 + k) * 512 + n * 128 + d0];
        float bx1 = ws[WS_BX + (t * 4 + k) * 512 + n * 128 + d1];

        // novelty / decay — redundantly per wave, pure intra-wave butterfly
        float x0 = xl[d0], x1 = xl[d1], m0 = mlL[d0], m1 = mlL[d1];
        float vx = x0 * x0 + x1 * x1, vm = m0 * m0 + m1 * m1, vd = x0 * m0 + x1 * m1;
        for (int m = 32; m; m >>= 1) { vx += __shfl_xor(vx, m); vm += __shfl_xor(vm, m); vd += __shfl_xor(vd, m); }
        float xnorm = sqrtf(vx) + EPSF, mnorm = sqrtf(vm) + EPSF;
        float nov = 1.0f - vd / (xnorm * mnorm);
        float novelty = (mnorm > 1e-8f) ? nov : 1.0f;
        const float dec = 1.0f / (1.0f + expf(-(dbase - sens * novelty)));

        float bm0 = bmmL[n][d0], bm1 = bmmL[n][d1];
        float e00 = bx0 + dec * bm0, e01 = bx1 + dec * bm1;
        float u0 = x0 + dec * m0, u1 = x1 + dec * m1;
        float a0 = 0.f, a1 = 0.f, be0 = 0.f, be1 = 0.f;
        exL[n][dG] = (h == 0) ? e00 : e01;
        __syncthreads();                               // B2: exL init

        for (int s = 0; s < 5; ++s) {
            float em0[4], em1[4];
#pragma unroll
            for (int m = 0; m < 4; ++m) { em0[m] = exL[m][d0]; em1[m] = exL[m][d1]; }
            float ex0 = em0[n], ex1 = em1[n];
            float r[5];
#pragma unroll
            for (int m = 0; m < 4; ++m) r[m] = ex0 * em0[m] + ex1 * em1[m];
            float t4 = u0 * u0 + u1 * u1;
            float t5 = (e00 + be0) * a0 + (e01 + be1) * a1;
            float t6 = a0 * (ex0 - e00 - be0) + a1 * (ex1 - e01 - be1);
            r[4] = t4 + 2.f * t5 + t6;                 // pre-combined norm accumulator
#pragma unroll
            for (int m2 = 32; m2; m2 >>= 1) {
#pragma unroll
                for (int q = 0; q < 5; ++q) r[q] += __shfl_xor(r[q], m2);
            }
            float sn = sqrtf(fmaxf(r[4], 0.f));
            if (lane == 0 && h == 0) { diagP[n] = r[n]; sP[n] = sn; }
            __syncthreads();                           // B3: 8-float exchange
            float ssum = ((sP[0] + sP[1]) + sP[2]) + sP[3];
            float cn = gate * (0.25f * ssum + EPSF) * 0.01f;

            float Pnn = r[n];
            float enn = sqrtf(fmaxf(Pnn, 0.f)) + EPSF;
            float fsh0 = 0.f, fsh1 = 0.f;
#pragma unroll
            for (int m = 0; m < 4; ++m) {
                float Pmm = diagP[m];
                float Pnm = r[m];
                float enm = sqrtf(fmaxf(Pmm, 0.f)) + EPSF;
                float cosnm = Pnm / (enn * enm);
                float fm = (cosnm - tgt) * w_inter[m];
                float dnn = sqrtf(fmaxf(Pnn - 2.f * Pnm + Pmm, 0.f)) + EPSF;
                float wq = fm / dnn;
                fsh0 += wq * (ex0 - em0[m]);
                fsh1 += wq * (ex1 - em1[m]);
            }
            a0 += stp * fsh0; a1 += stp * fsh1;
            be0 += cn * bep0[s]; be1 += cn * bep1[s];
            u0 += cn * no0[s];   u1 += cn * no1[s];
            // duplicate identical-value writes from both halves — benign;
            // each wave reads back only its OWN writes (wave-synchronous, no barrier)
            aL[n][d0] = a0; aL[n][d1] = a1;
            const float4* a4 = (const float4*)aL[n];
            float y = 0.f;
#pragma unroll
            for (int c = 0; c < 32; ++c) {
                float4 av = a4[c];
                y += gg[c].x * av.x + gg[c].y * av.y + gg[c].z * av.z + gg[c].w * av.w;
            }
            float exn = ((h == 0) ? e00 : e01) + y + ((h == 0) ? be0 : be1);
            exL[n][dG] = exn;
            __syncthreads();                           // B4: exL for next step
        }

        // eq(dG) = u(dG) + sum_j a[j] * B[j][dG]  (half the finalize work per lane)
        {
            const float* Bp = bases + (size_t)kn * 16384;
            float acc = 0.f;
#pragma unroll 8
            for (int j = 0; j < 128; ++j) acc += aL[n][j] * Bp[(size_t)j * 128 + dG];
            float eq = ((h == 0) ? u0 : u1) + acc;
            ws[WS_BEPS + t * 10240 + k * 2560 + n * 128 + dG] = eq;   // fp32 eq stash
            unsigned short* eqb = (unsigned short*)(ws + WS_EQBALL);
            {
                int c2 = dG >> 5, lg = (dG >> 3) & 3, j8 = dG & 7;
                eqb[t * 2048 + (c2 * 64 + lg * 16 + kn) * 8 + j8] = (unsigned short)bfb(eq);
            }
            float sq = eq * eq;
            for (int m = 32; m; m >>= 1) sq += __shfl_xor(sq, m);
            if (lane == 0) sq7[n][h] = sq;
            exL[n][dG] = eq;
            __syncthreads();                           // F1: eq + sq visible
            if (tid < 4) {
                float s4 = (sq7[0][0] + sq7[0][1]) + (sq7[1][0] + sq7[1][1])
                         + (sq7[2][0] + sq7[2][1]) + (sq7[3][0] + sq7[3][1]);
                ws[WS_WK + t * 16 + 4 * k + tid] = 1.0f / (4.0f * (s4 + EPSF));
            }
            if (n == 0) {    // waves 0 (dims 0-63) and 4 (dims 64-127)
                float eqm = 0.25f * (exL[0][dG] + exL[1][dG] + exL[2][dG] + exL[3][dG]);
                mlL[dG] = dec * mlL[dG] + (1.f - dec) * eqm;
            }
            __syncthreads();                           // F2: mm
            // bmm[kn][dG] = B[kn] row dG . mm  (one row per lane, into LDS)
            const float4* Br = (const float4*)(bases + (size_t)kn * 16384 + (size_t)dG * 128);
            const float4* mm4 = (const float4*)mlL;
            float bacc = 0.f;
#pragma unroll 8
            for (int c = 0; c < 32; ++c) {
                float4 mv = mm4[c];
                float4 bv = Br[c];
                bacc += bv.x * mv.x + bv.y * mv.y + bv.z * mv.z + bv.w * mv.w;
            }
            bmmL[n][dG] = bacc;       // next-token B1 covers visibility
        }
    }
}

// ---------------- mega: blocks 0-15 = Gram+Jacobi (overlap GEMM); 16+ = logits GEMM, 8 tokens/block ----------------
__global__ __launch_bounds__(256, 2)
void mega(const float* __restrict__ E, float* __restrict__ ws, float* __restrict__ out)
{
    int b = blockIdx.x, tid = threadIdx.x;
    if (b < 16) {
        int tt = b;
        __shared__ float Gsh[256];
        __shared__ float Am[16 * 20];
        __shared__ float cR[16], sR[16];
        {   // Gram from fp32 eq stash (all 256 threads, one entry each)
            int i = tid >> 4, j = tid & 15;
            const float4* ra = (const float4*)(ws + WS_BEPS + tt * 10240 + (i >> 2) * 2560 + (i & 3) * 128);
            const float4* rb = (const float4*)(ws + WS_BEPS + tt * 10240 + (j >> 2) * 2560 + (j & 3) * 128);
            float dp = 0.f;
#pragma unroll 8
            for (int c = 0; c < 32; ++c) {
                float4 a = ra[c], b2 = rb[c];
                dp += a.x * b2.x + a.y * b2.y + a.z * b2.z + a.w * b2.w;
            }
            Gsh[tid] = dp;
        }
        __syncthreads();
        if (tid >= 64) return;
        const float* G = Gsh;
        int i0 = tid >> 2, j40 = (tid & 3) * 4;
        float wv4[4];
#pragma unroll
        for (int kk = 0; kk < 4; ++kk) {
            float ss = G[(4*kk+0)*17] + G[(4*kk+1)*17] + G[(4*kk+2)*17] + G[(4*kk+3)*17];
            wv4[kk] = 1.0f / (4.0f * (ss + EPSF));
        }
#pragma unroll
        for (int m = 0; m < 4; ++m) {
            int jjv = j40 + m;
            Am[i0 * 20 + jjv] = sqrtf(wv4[i0 >> 2] * wv4[jjv >> 2]) * G[i0 * 16 + jjv];
        }
        for (int sw = 0; sw < 6; ++sw) {
            for (int r = 0; r < 15; ++r) {
                if (tid < 8) {
                    int p, q;
                    if (tid == 0) { p = 15; q = r % 15; }
                    else { p = (r + tid) % 15; q = (r - tid + 15) % 15; }
                    float c, s;
                    rotfast(Am[p * 20 + p], Am[q * 20 + q], Am[p * 20 + q], c, s);
                    cR[p] = c; sR[p] = -s;
                    cR[q] = c; sR[q] = s;
                }
                int oi; bool ip; jpair(i0, r, oi, ip);
                float ci = cR[i0], siS = sR[i0];
                float nv[4];
#pragma unroll
                for (int m = 0; m < 4; ++m) {
                    int jjv = j40 + m;
                    int oj; bool jp2; jpair(jjv, r, oj, jp2);
                    float cj = cR[jjv], sjS = sR[jjv];
                    float a00 = Am[i0 * 20 + jjv], a01 = Am[i0 * 20 + oj];
                    float a10 = Am[oi * 20 + jjv], a11 = Am[oi * 20 + oj];
                    nv[m] = ci*cj*a00 + ci*sjS*a01 + siS*cj*a10 + siS*sjS*a11;
                }
#pragma unroll
                for (int m = 0; m < 4; ++m) Am[i0 * 20 + j40 + m] = nv[m];
            }
        }
        if (tid == 0) {
            float tot = 112.0f * 1e-12f;
            float lc[16];
            for (int a2 = 0; a2 < 16; ++a2) { lc[a2] = fmaxf(Am[a2 * 20 + a2], 1e-12f); tot += lc[a2]; }
            float S = 0.f;
            for (int a2 = 0; a2 < 16; ++a2) { float pp = lc[a2] / tot; S -= pp * fmaxf(logf(pp), -100.f); }
            float p0 = 1e-12f / tot;
            S -= 112.f * p0 * fmaxf(logf(p0), -100.f);
            out[(size_t)T_ * V_ + tt] = S;
            ws[WS_SRHO + tt] = S;
        }
        return;
    }
    int b2 = b - 16;
    int pass = b2 / 500;                 // 0 or 1
    int bb = b2 - pass * 500;
    int tok0 = pass * 8;
    int lane = tid & 63, wv = tid >> 6;
    const short8v* eqB = (const short8v*)(ws + WS_EQBALL);
    short8v bfr[8][4];
#pragma unroll
    for (int tk = 0; tk < 8; ++tk)
#pragma unroll
        for (int c2 = 0; c2 < 4; ++c2) bfr[tk][c2] = eqB[(tok0 + tk) * 256 + c2 * 64 + lane];
    float wk[8], zl[8];
#pragma unroll
    for (int tk = 0; tk < 8; ++tk) {
        wk[tk] = ws[WS_WK + (tok0 + tk) * 16 + (lane & 15)];
        zl[tk] = 0.f;
    }
    int tilebase = (bb * 4 + wv) * 64;
#pragma unroll
    for (int it = 0; it < 4; ++it) {
        int rowB = tilebase + it * 16;
        const float* Erow = E + (size_t)(rowB + (lane & 15)) * 128 + ((lane >> 4) * 8);
        float4v acc[8];
#pragma unroll
        for (int tk = 0; tk < 8; ++tk) acc[tk] = (float4v){0.f, 0.f, 0.f, 0.f};
#pragma unroll
        for (int c2 = 0; c2 < 4; ++c2) {
            float4 e0 = *((const float4*)(Erow + c2 * 32));
            float4 e1 = *((const float4*)(Erow + c2 * 32 + 4));
            short8v a;
            a[0] = bfb(e0.x); a[1] = bfb(e0.y); a[2] = bfb(e0.z); a[3] = bfb(e0.w);
            a[4] = bfb(e1.x); a[5] = bfb(e1.y); a[6] = bfb(e1.z); a[7] = bfb(e1.w);
#pragma unroll
            for (int tk = 0; tk < 8; ++tk)
                acc[tk] = __builtin_amdgcn_mfma_f32_16x16x32_bf16(a, bfr[tk][c2], acc[tk], 0, 0, 0);
        }
#pragma unroll
        for (int tk = 0; tk < 8; ++tk) {
            float l0 = wk[tk] * acc[tk][0] * acc[tk][0];
            float l1 = wk[tk] * acc[tk][1] * acc[tk][1];
            float l2 = wk[tk] * acc[tk][2] * acc[tk][2];
            float l3 = wk[tk] * acc[tk][3] * acc[tk][3];
#pragma unroll
            for (int m = 1; m <= 8; m <<= 1) {
                l0 += __shfl_xor(l0, m); l1 += __shfl_xor(l1, m);
                l2 += __shfl_xor(l2, m); l3 += __shfl_xor(l3, m);
            }
            if ((lane & 15) == 0) {
                float4 st; st.x = l0; st.y = l1; st.z = l2; st.w = l3;
                *((float4*)(out + (size_t)(tok0 + tk) * V_ + rowB + (lane >> 4) * 4)) = st;
                zl[tk] += __expf(l0) + __expf(l1) + __expf(l2) + __expf(l3);
            }
        }
    }
#pragma unroll
    for (int tk = 0; tk < 8; ++tk) {
        float z = zl[tk];
        z += __shfl_xor(z, 16); z += __shfl_xor(z, 32);
        if (lane == 0) ws[WS_ZPART + (tok0 + tk) * 2000 + bb * 4 + wv] = z;
    }
}

// ---------------- zk: Z reduce per token ----------------
__global__ __launch_bounds__(256)
void zk(float* __restrict__ ws)
{
    int b = blockIdx.x, tid = threadIdx.x;
    double s = 0.0;
    for (int i = tid; i < 2000; i += 256) s += (double)ws[WS_ZPART + b * 2000 + i];
    for (int m = 32; m; m >>= 1) s += __shfl_xor(s, m);
    __shared__ double sr[4];
    if ((tid & 63) == 0) sr[tid >> 6] = s;
    __syncthreads();
    if (tid == 0) ws[WS_LNZ + b] = (float)log(sr[0] + sr[1] + sr[2] + sr[3]);
}

// ---------------- fin1: probs + per-block H partials (pure streaming) ----------------
__global__ __launch_bounds__(256)
void fin1(float* __restrict__ ws, float* __restrict__ out)
{
    int b = blockIdx.x, tid = threadIdx.x;
    int tt = b / 125, blk = b - tt * 125;
    int v = blk * 1024 + tid * 4;
    float lnZ = ws[WS_LNZ + tt];
    float* po = out + (size_t)tt * V_ + v;
    float4 l4 = *((const float4*)po);
    float lp0 = l4.x - lnZ, lp1 = l4.y - lnZ, lp2 = l4.z - lnZ, lp3 = l4.w - lnZ;
    float p0 = __expf(lp0), p1 = __expf(lp1), p2 = __expf(lp2), p3 = __expf(lp3);
    float4 st; st.x = p0; st.y = p1; st.z = p2; st.w = p3;
    *((float4*)po) = st;
    float hp = p0 * fmaxf(lp0, -100.f) + p1 * fmaxf(lp1, -100.f)
             + p2 * fmaxf(lp2, -100.f) + p3 * fmaxf(lp3, -100.f);
    for (int m = 32; m; m >>= 1) hp += __shfl_xor(hp, m);
    __shared__ float hr[4];
    if ((tid & 63) == 0) hr[tid >> 6] = hp;
    __syncthreads();
    if (tid == 0) ws[WS_HPART + tt * 125 + blk] = hr[0] + hr[1] + hr[2] + hr[3];
}

// ---------------- f2: per-token H reduction ----------------
__global__ __launch_bounds__(128)
void f2_final(float* __restrict__ ws, float* __restrict__ out)
{
    int t = blockIdx.x, tid = threadIdx.x;
    float s = (tid < 125) ? ws[WS_HPART + t * 125 + tid] : 0.f;
    for (int m = 32; m; m >>= 1) s += __shfl_xor(s, m);
    __shared__ float sr[2];
    if ((tid & 63) == 0) sr[tid >> 6] = s;
    __syncthreads();
    if (tid == 0) {
        float H = -(sr[0] + sr[1]);
        float S = ws[WS_SRHO + t];
        out[(size_t)T_ * V_ + T_ + t] = H;
        out[(size_t)T_ * V_ + 2 * T_ + t] = H - S;
    }
}

extern "C" void kernel_launch(void* const* d_in, const int* in_sizes, int n_in,
                              void* d_out, int out_size, void* d_ws, size_t ws_size,
                              hipStream_t stream)
{
    (void)in_sizes; (void)n_in; (void)out_size; (void)ws_size;
    const float* E           = (const float*)d_in[0];
    const float* bases       = (const float*)d_in[1];
    const float* tension     = (const float*)d_in[2];
    const float* temperature = (const float*)d_in[3];
    const float* target_sim  = (const float*)d_in[4];
    const float* step_size   = (const float*)d_in[5];
    const float* gate_logit  = (const float*)d_in[6];
    const float* decay_base  = (const float*)d_in[7];
    const float* sensitivity = (const float*)d_in[8];
    const float* noise       = (const float*)d_in[9];
    const int*   tokens      = (const int*)d_in[10];
    float* out = (float*)d_out;
    float* ws  = (float*)d_ws;

    i2_prep<<<65, 256, 0, stream>>>(bases, E, noise, tokens, tension, temperature, ws);
    kap_all<<<4, 512, 0, stream>>>(E, noise, tokens, bases, target_sim, step_size,
                                   gate_logit, decay_base, sensitivity, ws);
    mega<<<1016, 256, 0, stream>>>(E, ws, out);
    zk<<<16, 256, 0, stream>>>(ws);
    fin1<<<T_ * 125, 256, 0, stream>>>(ws, out);
    f2_final<<<T_, 128, 0, stream>>>(ws, out);
}